// Round 5
// baseline (329.383 us; speedup 1.0000x reference)
//
#include <hip/hip_runtime.h>
#include <hip/hip_bf16.h>

// B=64, T=128, D=512. gates = x @ w_ih^T per t; f-gate unused (c0=0).
// Single fused kernel: per-(t, 64-col) block.
//   - convert x[t] rows to bf16 hi/lo frags in VGPRs (once per block)
//   - 12 substages: DMA 16 w-rows (32KB, sequential) into swizzled dbuf LDS
//     via global_load_lds; VMEM-free compute phase (bf16x3 MFMA)
//   - LSTM activation fused, h -> d_out
//   - last block per t (atomic counter) softmaxes t's 64x512 slice in place
//     (L2-hot: same-XCD by swizzle; correct regardless via agent fences).

#define B_ 64
#define T_ 128
#define D_ 512

typedef float f32x4_t __attribute__((ext_vector_type(4)));
typedef __bf16 bf16x8_t __attribute__((ext_vector_type(8)));
typedef unsigned short u16x8_t __attribute__((ext_vector_type(8)));
typedef unsigned int u32;
typedef const __attribute__((address_space(1))) u32* gp_t;
typedef __attribute__((address_space(3))) u32* lp_t;

#define GLOAD_LDS16(g, l) \
  __builtin_amdgcn_global_load_lds((gp_t)(const void*)(g), (lp_t)(void*)(l), 16, 0, 0)

// Round-to-nearest split: f = hi + lo + O(2^-18 |f|).
__device__ __forceinline__ void cvt8(float4 a, float4 b, u16x8_t& hi, u16x8_t& lo) {
  float f[8] = {a.x, a.y, a.z, a.w, b.x, b.y, b.z, b.w};
#pragma unroll
  for (int j = 0; j < 8; ++j) {
    __bf16 h = (__bf16)f[j];
    hi[j] = __builtin_bit_cast(unsigned short, h);
    float r = f[j] - (float)h;
    __bf16 l = (__bf16)r;
    lo[j] = __builtin_bit_cast(unsigned short, l);
  }
}

__device__ __forceinline__ f32x4_t mfma16(u16x8_t a, u16x8_t b, f32x4_t c) {
  return __builtin_amdgcn_mfma_f32_16x16x32_bf16(
      __builtin_bit_cast(bf16x8_t, a), __builtin_bit_cast(bf16x8_t, b), c, 0, 0, 0);
}

__device__ __forceinline__ float sigmoid_f(float v) { return 1.0f / (1.0f + __expf(-v)); }
__device__ __forceinline__ float tanh_f(float v) { return 1.0f - 2.0f / (__expf(2.0f * v) + 1.0f); }

// Grid 1024 = 128 t x 8 d-tiles. 4 waves; wave wv owns b-rows [wv*16,+16).
__global__ __launch_bounds__(256, 2) void lstm_fused_kernel(
    const float* __restrict__ x, const float* __restrict__ w,
    float* __restrict__ out, int* __restrict__ cnt) {
  __shared__ float lds[2][8192];  // 2 x 32KB (16 w-rows of 512 f32, XOR-swizzled)
  __shared__ int is_last;
  const int lane = threadIdx.x & 63;
  const int wv = threadIdx.x >> 6;
  const int bid = blockIdx.x;
  // XCD swizzle: the 8 d-tiles of each t share an XCD (x slice + h slice L2-resident).
  const int work = (bid & 7) * 128 + (bid >> 3);
  const int t = work >> 3;
  const int d0 = (work & 7) << 6;

  const int c = lane & 15;   // frag row/col index
  const int kg = lane >> 4;  // k-subgroup 0..3

  // ---- x A-frag build: b-row = wv*16 + c; step st covers k in [st*32,+32),
  // this lane holds k = st*32 + kg*8 + j. x[t] slice is 8x-reused across blocks (L2).
  const float* xrow = x + (((size_t)(wv * 16 + c) * T_ + t) << 9) + kg * 8;
  u16x8_t xh[16], xl[16];
#pragma unroll
  for (int st = 0; st < 16; ++st) {
    float4 a = *(const float4*)(xrow + st * 32);
    float4 b = *(const float4*)(xrow + st * 32 + 4);
    cvt8(a, b, xh[st], xl[st]);
  }

  // ---- DMA source offsets (pre-swizzled global so linear DMA lands swizzled).
  // LDS slot P (byte in 32KB tile) holds content linear L = P ^ ((row(P)&7)<<4).
  unsigned soff[8];
#pragma unroll
  for (int i = 0; i < 8; ++i) {
    unsigned P = (unsigned)(wv * 8192 + i * 1024 + lane * 16);
    soff[i] = P ^ (((P >> 11) & 7) << 4);
  }

  // ---- fragment read bases: linear byte = c*2048 + kg*32 (+16) (+ st*128 imm).
  const unsigned sw = (unsigned)((c & 7) << 4);
  const unsigned rb0 = ((unsigned)(c * 2048 + kg * 32)) ^ sw;
  const unsigned rb1 = ((unsigned)(c * 2048 + kg * 32 + 16)) ^ sw;

  // substage s: gate g = s>>2 (w-row base 0/1024/1536), col-group cg = s&3.
  const unsigned sboff[12] = {
      (0u + 0 * 16) * 2048u,    (0u + 1 * 16) * 2048u,    (0u + 2 * 16) * 2048u,    (0u + 3 * 16) * 2048u,
      (1024u + 0 * 16) * 2048u, (1024u + 1 * 16) * 2048u, (1024u + 2 * 16) * 2048u, (1024u + 3 * 16) * 2048u,
      (1536u + 0 * 16) * 2048u, (1536u + 1 * 16) * 2048u, (1536u + 2 * 16) * 2048u, (1536u + 3 * 16) * 2048u};
  const char* wbytes = (const char*)w + ((size_t)t << 22) + (size_t)d0 * 2048;

  f32x4_t acc[12];
#pragma unroll
  for (int s = 0; s < 12; ++s) acc[s] = (f32x4_t){0.f, 0.f, 0.f, 0.f};

  // ---- prologue DMA(0)
  {
    const char* gb = wbytes + sboff[0];
    char* lb = (char*)&lds[0][0] + wv * 8192;
#pragma unroll
    for (int i = 0; i < 8; ++i) GLOAD_LDS16(gb + soff[i], lb + i * 1024);
  }

#pragma unroll
  for (int s = 0; s < 12; ++s) {
    if (s < 11) {  // DMA(s+1) into the other buffer
      const char* gb = wbytes + sboff[s + 1];
      char* lb = (char*)&lds[(s + 1) & 1][0] + wv * 8192;
#pragma unroll
      for (int i = 0; i < 8; ++i) GLOAD_LDS16(gb + soff[i], lb + i * 1024);
    }
    __builtin_amdgcn_sched_barrier(0);
    if (s < 11) asm volatile("s_waitcnt vmcnt(8)" ::: "memory");  // DMA(s) retired
    else        asm volatile("s_waitcnt vmcnt(0)" ::: "memory");
    __builtin_amdgcn_s_barrier();  // buf[s&1] visible to all waves
    __builtin_amdgcn_sched_barrier(0);

    const char* lb = (const char*)&lds[s & 1][0];
    __builtin_amdgcn_s_setprio(1);
#pragma unroll
    for (int st = 0; st < 16; ++st) {
      float4 wa = *(const float4*)(lb + rb0 + st * 128);
      float4 wb = *(const float4*)(lb + rb1 + st * 128);
      u16x8_t wh, wl;
      cvt8(wa, wb, wh, wl);
      acc[s] = mfma16(xh[st], wh, acc[s]);
      acc[s] = mfma16(xh[st], wl, acc[s]);
      acc[s] = mfma16(xl[st], wh, acc[s]);
    }
    __builtin_amdgcn_s_setprio(0);
    __builtin_amdgcn_sched_barrier(0);
    __builtin_amdgcn_s_barrier();  // all waves done reading buf[s&1]
  }

  // ---- LSTM activation + h write. C frag: col = c, row = kg*4 + j.
#pragma unroll
  for (int cg = 0; cg < 4; ++cg) {
#pragma unroll
    for (int j = 0; j < 4; ++j) {
      float iv = acc[cg][j];
      float gv = acc[4 + cg][j];
      float ov = acc[8 + cg][j];
      float cc = sigmoid_f(iv) * tanh_f(gv);
      float h = sigmoid_f(ov) * tanh_f(cc);
      int b = wv * 16 + kg * 4 + j;
      int dcol = d0 + cg * 16 + c;
      out[(((size_t)b * T_ + t) << 9) + dcol] = h;
    }
  }

  // ---- last block of this t does the softmax for all 64 rows, in place.
  __threadfence();      // release: my h stores visible device-wide
  __syncthreads();      // all threads of block have fenced
  if (threadIdx.x == 0) is_last = (atomicAdd(&cnt[t], 1) == 7);
  __syncthreads();
  if (!is_last) return;
  __threadfence();      // acquire: other blocks' h stores visible

  // wave wv handles rows b = wv*16 + i; row data L2-hot (same XCD).
  for (int i = 0; i < 16; ++i) {
    float* p = out + (((size_t)(wv * 16 + i) * T_ + t) << 9);
    float4 v0 = *(const float4*)(p + lane * 4);
    float4 v1 = *(const float4*)(p + 256 + lane * 4);
    float l[8] = {20.f * v0.x, 20.f * v0.y, 20.f * v0.z, 20.f * v0.w,
                  20.f * v1.x, 20.f * v1.y, 20.f * v1.z, 20.f * v1.w};
    float m = l[0];
#pragma unroll
    for (int j = 1; j < 8; ++j) m = fmaxf(m, l[j]);
#pragma unroll
    for (int o = 32; o > 0; o >>= 1) m = fmaxf(m, __shfl_xor(m, o, 64));
    float e[8], sum = 0.f;
#pragma unroll
    for (int j = 0; j < 8; ++j) {
      e[j] = __expf(l[j] - m);
      sum += e[j];
    }
#pragma unroll
    for (int o = 32; o > 0; o >>= 1) sum += __shfl_xor(sum, o, 64);
    float inv = 1.0f / sum;
    float4 o0 = {e[0] * inv, e[1] * inv, e[2] * inv, e[3] * inv};
    float4 o1 = {e[4] * inv, e[5] * inv, e[6] * inv, e[7] * inv};
    *(float4*)(p + lane * 4) = o0;
    *(float4*)(p + 256 + lane * 4) = o1;
  }
}

extern "C" void kernel_launch(void* const* d_in, const int* in_sizes, int n_in,
                              void* d_out, int out_size, void* d_ws, size_t ws_size,
                              hipStream_t stream) {
  const float* x = (const float*)d_in[0];
  const float* w = (const float*)d_in[1];
  float* out = (float*)d_out;
  int* cnt = (int*)d_ws;  // T_ counters

  hipMemsetAsync(cnt, 0, T_ * sizeof(int), stream);
  lstm_fused_kernel<<<T_ * 8, 256, 0, stream>>>(x, w, out, cnt);
}

// Round 6
// 125.664 us; speedup vs baseline: 2.6211x; 2.6211x over previous
//
#include <hip/hip_runtime.h>
#include <hip/hip_bf16.h>

// B=64, T=128, D=512. gates = x @ w_ih^T per t; f-gate unused (c0=0).
// K1: per-(t, 64-col) block, 4 waves, 2 blocks/CU (VGPR-limited by design).
//     x[t] rows converted ONCE to bf16 hi/lo frags held in 128 VGPRs (true
//     register residency -> compute phases have zero VMEM).
//     24 substages (3 gates x 4 col-groups x 2 K-halves): each stages 16 w-rows
//     x 1KB (sequential HBM) into a 16KB LDS buffer via global_load_lds,
//     triple-buffered, prefetch depth 2, counted vmcnt(8).
//     bf16x3 MFMA (hi*hi + hi*lo + lo*hi); LSTM activation fused; h -> d_out.
// K2: separate in-place softmax(20*h). NO device fences/atomics anywhere.

#define B_ 64
#define T_ 128
#define D_ 512

typedef float f32x4_t __attribute__((ext_vector_type(4)));
typedef __bf16 bf16x8_t __attribute__((ext_vector_type(8)));
typedef unsigned short u16x8_t __attribute__((ext_vector_type(8)));
typedef unsigned int u32;
typedef const __attribute__((address_space(1))) u32* gp_t;
typedef __attribute__((address_space(3))) u32* lp_t;

#define GLOAD_LDS16(g, l) \
  __builtin_amdgcn_global_load_lds((gp_t)(const void*)(g), (lp_t)(void*)(l), 16, 0, 0)

// Round-to-nearest split: f = hi + lo + O(2^-18 |f|).
__device__ __forceinline__ void cvt8(float4 a, float4 b, u16x8_t& hi, u16x8_t& lo) {
  float f[8] = {a.x, a.y, a.z, a.w, b.x, b.y, b.z, b.w};
#pragma unroll
  for (int j = 0; j < 8; ++j) {
    __bf16 h = (__bf16)f[j];
    hi[j] = __builtin_bit_cast(unsigned short, h);
    float r = f[j] - (float)h;
    __bf16 l = (__bf16)r;
    lo[j] = __builtin_bit_cast(unsigned short, l);
  }
}

__device__ __forceinline__ f32x4_t mfma16(u16x8_t a, u16x8_t b, f32x4_t c) {
  return __builtin_amdgcn_mfma_f32_16x16x32_bf16(
      __builtin_bit_cast(bf16x8_t, a), __builtin_bit_cast(bf16x8_t, b), c, 0, 0, 0);
}

__device__ __forceinline__ float sigmoid_f(float v) { return 1.0f / (1.0f + __expf(-v)); }
__device__ __forceinline__ float tanh_f(float v) { return 1.0f - 2.0f / (__expf(2.0f * v) + 1.0f); }

// Grid 1024 = 128 t x 8 d-tiles. Wave wv owns b-rows [wv*16, +16).
__global__ __launch_bounds__(256, 2) void lstm_gates_kernel(
    const float* __restrict__ x, const float* __restrict__ w,
    float* __restrict__ out) {
  __shared__ float lds[3][4096];  // 3 x 16KB (16 w-rows x 256-float K-half, swizzled)
  const int lane = threadIdx.x & 63;
  const int wv = threadIdx.x >> 6;
  const int bid = blockIdx.x;
  // XCD swizzle: the 8 d-tiles of each t share an XCD -> x[t] slice L2-resident.
  const int work = (bid & 7) * 128 + (bid >> 3);
  const int t = work >> 3;
  const int d0 = (work & 7) << 6;

  const int c = lane & 15;   // frag row/col index
  const int kg = lane >> 4;  // k-subgroup 0..3

  // ---- x A-frag build, held in VGPRs for the whole kernel (128 regs).
  // b-row = wv*16 + c; step st covers k [st*32,+32); lane holds k=st*32+kg*8+j.
  const float* xrow = x + (((size_t)(wv * 16 + c) * T_ + t) << 9) + kg * 8;
  u16x8_t xh[16], xl[16];
#pragma unroll
  for (int st = 0; st < 16; ++st) {
    float4 a = *(const float4*)(xrow + st * 32);
    float4 b = *(const float4*)(xrow + st * 32 + 4);
    cvt8(a, b, xh[st], xl[st]);
  }
  asm volatile("s_waitcnt vmcnt(0)" ::: "memory");  // clean vmcnt before DMA pipeline

  // ---- DMA per-lane source offsets for this wave's 4 rows (pre-swizzled:
  // LDS slot P holds linear L = P ^ ((row(P)&7)<<4); dst stays linear).
  unsigned soff[4];
#pragma unroll
  for (int i = 0; i < 4; ++i) {
    int r = wv * 4 + i;
    soff[i] = (unsigned)(lane * 16) ^ (unsigned)((r & 7) << 4);
  }

  // w[t] row base (within-t row index) per gate: i=0, g=2D, o=3D; f skipped.
  const int grow[3] = {0, 1024, 1536};
  const char* wbytes = (const char*)w + ((size_t)t << 22) + (size_t)d0 * 2048;

  // substage ss = (g*4 + cg)*2 + kh: gate g, col-group cg (16 cols), K-half kh.
#define DMA_STAGE(SS, BB)                                                             \
  do {                                                                                \
    const int g_ = (SS) >> 3, cg_ = ((SS) >> 1) & 3, kh_ = (SS) & 1;                  \
    const char* gb_ =                                                                 \
        wbytes + (size_t)(grow[g_] + cg_ * 16 + wv * 4) * 2048 + (size_t)kh_ * 1024;  \
    char* lb_ = (char*)&lds[BB][0] + wv * 4096;                                       \
    GLOAD_LDS16(gb_ + 0 * 2048 + soff[0], lb_ + 0);                                   \
    GLOAD_LDS16(gb_ + 1 * 2048 + soff[1], lb_ + 1024);                                \
    GLOAD_LDS16(gb_ + 2 * 2048 + soff[2], lb_ + 2048);                                \
    GLOAD_LDS16(gb_ + 3 * 2048 + soff[3], lb_ + 3072);                                \
  } while (0)

  f32x4_t acc[12];
#pragma unroll
  for (int s = 0; s < 12; ++s) acc[s] = (f32x4_t){0.f, 0.f, 0.f, 0.f};

  // ---- prologue: 2 substages in flight
  DMA_STAGE(0, 0);
  DMA_STAGE(1, 1);

  const unsigned sw = (unsigned)((c & 7) << 4);
  const unsigned rbase = (unsigned)(c * 1024);

#pragma unroll
  for (int ss = 0; ss < 24; ++ss) {
    const int g = ss >> 3, cg = (ss >> 1) & 3, kh = ss & 1;
    const int bb = ss % 3;
    if (ss + 2 < 24) DMA_STAGE(ss + 2, (ss + 2) % 3);
    __builtin_amdgcn_sched_barrier(0);
    if (ss <= 21)      asm volatile("s_waitcnt vmcnt(8)" ::: "memory");  // DMA(ss) done
    else if (ss == 22) asm volatile("s_waitcnt vmcnt(4)" ::: "memory");
    else               asm volatile("s_waitcnt vmcnt(0)" ::: "memory");
    __builtin_amdgcn_s_barrier();  // buf bb visible to all waves
    __builtin_amdgcn_sched_barrier(0);

    const char* lb = (const char*)&lds[bb][0];
    const int ai = g * 4 + cg;
#pragma unroll
    for (int st = 0; st < 8; ++st) {
      float4 wa = *(const float4*)(lb + rbase + ((unsigned)(st * 128 + kg * 32) ^ sw));
      float4 wb = *(const float4*)(lb + rbase + ((unsigned)(st * 128 + kg * 32 + 16) ^ sw));
      u16x8_t wh, wl;
      cvt8(wa, wb, wh, wl);
      acc[ai] = mfma16(xh[kh * 8 + st], wh, acc[ai]);
      acc[ai] = mfma16(xh[kh * 8 + st], wl, acc[ai]);
      acc[ai] = mfma16(xl[kh * 8 + st], wh, acc[ai]);
    }
    __builtin_amdgcn_sched_barrier(0);
    __builtin_amdgcn_s_barrier();  // all waves done reading buf bb
  }
#undef DMA_STAGE

  // ---- LSTM activation + h write. C frag: col = c, row = kg*4 + j.
#pragma unroll
  for (int cg = 0; cg < 4; ++cg) {
#pragma unroll
    for (int j = 0; j < 4; ++j) {
      float iv = acc[cg][j];
      float gv = acc[4 + cg][j];
      float ov = acc[8 + cg][j];
      float cc = sigmoid_f(iv) * tanh_f(gv);
      float h = sigmoid_f(ov) * tanh_f(cc);
      int b = wv * 16 + kg * 4 + j;
      int dcol = d0 + cg * 16 + c;
      out[(((size_t)b * T_ + t) << 9) + dcol] = h;
    }
  }
}

// One wave per (b,t) row of 512; in-place softmax(20*h).
__global__ __launch_bounds__(256) void softmax_kernel(float* __restrict__ io) {
  const int lane = threadIdx.x & 63;
  const int row = blockIdx.x * 4 + (threadIdx.x >> 6);
  float* p = io + ((size_t)row << 9);
  float4 v0 = *(const float4*)(p + lane * 4);
  float4 v1 = *(const float4*)(p + 256 + lane * 4);
  float l[8] = {20.f * v0.x, 20.f * v0.y, 20.f * v0.z, 20.f * v0.w,
                20.f * v1.x, 20.f * v1.y, 20.f * v1.z, 20.f * v1.w};
  float m = l[0];
#pragma unroll
  for (int j = 1; j < 8; ++j) m = fmaxf(m, l[j]);
#pragma unroll
  for (int o = 32; o > 0; o >>= 1) m = fmaxf(m, __shfl_xor(m, o, 64));
  float e[8], s = 0.f;
#pragma unroll
  for (int j = 0; j < 8; ++j) {
    e[j] = __expf(l[j] - m);
    s += e[j];
  }
#pragma unroll
  for (int o = 32; o > 0; o >>= 1) s += __shfl_xor(s, o, 64);
  float inv = 1.0f / s;
  float4 o0 = {e[0] * inv, e[1] * inv, e[2] * inv, e[3] * inv};
  float4 o1 = {e[4] * inv, e[5] * inv, e[6] * inv, e[7] * inv};
  *(float4*)(p + lane * 4) = o0;
  *(float4*)(p + 256 + lane * 4) = o1;
}

extern "C" void kernel_launch(void* const* d_in, const int* in_sizes, int n_in,
                              void* d_out, int out_size, void* d_ws, size_t ws_size,
                              hipStream_t stream) {
  const float* x = (const float*)d_in[0];
  const float* w = (const float*)d_in[1];
  float* out = (float*)d_out;
  lstm_gates_kernel<<<T_ * 8, 256, 0, stream>>>(x, w, out);
  softmax_kernel<<<(B_ * T_) / 4, 256, 0, stream>>>(out);
}